// Round 8
// baseline (5123.835 us; speedup 1.0000x reference)
//
#include <hip/hip_runtime.h>
#include <hip/hip_fp16.h>

#define TT 256
#define NSL 8           // slices (blocks) per batch element
#define KR 64           // enc k-rows per slice
#define NPAD 10112

typedef _Float16 f16;
typedef _Float16 f16x8 __attribute__((ext_vector_type(8)));
typedef float f32x2 __attribute__((ext_vector_type(2)));
typedef float f32x4 __attribute__((ext_vector_type(4)));

// ---- per-b exchange layout (floats, within one parity region) ----
#define H0_OFF 0        // 256: h0 full (8 x 32)
#define T1_OFF 256      // 8 tags
#define PP_OFF 272      // 8 x 512 proj partials
#define T2_OFF 4368     // 8 tags
#define MS_OFF 4400     // 8 x (m,S)
#define CP_OFF 4416     // 8 x 512 ctx partials
#define T3_OFF 8512     // 8 tags
#define PAR_STRIDE 8576
#define XC_STRIDE 17408ull

// ---- ws layout (bytes) ----
#define GE_OFF 4096ull
#define GE_BYTES (8192ull*1024ull*4ull)
#define XC_OFF (GE_OFF + GE_BYTES)
#define XC_BYTES (32ull*XC_STRIDE*4ull)
#define PC_OFF (XC_OFF + XC_BYTES)
#define PC_BYTES (8192ull*1024ull*2ull)
#define WO_OFF (PC_OFF + PC_BYTES)

__device__ __forceinline__ float sigm(float x) { return 1.f / (1.f + __expf(-x)); }

// ---- raw MALL-coherent (sc0 sc1) primitives ----
__device__ __forceinline__ void st1w(float* p, float v) {
  asm volatile("global_store_dword %0, %1, off sc0 sc1\n\ts_waitcnt vmcnt(0)"
               :: "v"(p), "v"(v) : "memory");
}
__device__ __forceinline__ void st1w2(float* p0, float v0, float* p1, float v1) {
  asm volatile(
    "global_store_dword %0, %1, off sc0 sc1\n\t"
    "global_store_dword %2, %3, off sc0 sc1\n\t"
    "s_waitcnt vmcnt(0)"
    :: "v"(p0), "v"(v0), "v"(p1), "v"(v1) : "memory");
}
__device__ __forceinline__ void st2w(float* p, f32x2 v) {
  asm volatile("global_store_dwordx2 %0, %1, off sc0 sc1\n\ts_waitcnt vmcnt(0)"
               :: "v"(p), "v"(v) : "memory");
}
__device__ __forceinline__ void st_tag(int* p, int v) {
  asm volatile("global_store_dword %0, %1, off sc0 sc1" :: "v"(p), "v"(v) : "memory");
}
__device__ __forceinline__ int ld_tag(const int* p) {
  int r;
  asm volatile("global_load_dword %0, %1, off sc0 sc1\n\ts_waitcnt vmcnt(0)"
               : "=v"(r) : "v"(p) : "memory");
  return r;
}
__device__ __forceinline__ float ld1(const float* p) {
  float r;
  asm volatile("global_load_dword %0, %1, off sc0 sc1\n\ts_waitcnt vmcnt(0)"
               : "=v"(r) : "v"(p) : "memory");
  return r;
}
// paired 8+8 loads at 512-float stride (4 VGPR-pair bases each + offset:2048), ONE waitcnt
__device__ __forceinline__ void ld8x2w(const float* a, const float* b,
                                       float* oa, float* ob) {
  asm volatile(
    "global_load_dword %0, %16, off sc0 sc1\n\t"
    "global_load_dword %1, %16, off offset:2048 sc0 sc1\n\t"
    "global_load_dword %2, %17, off sc0 sc1\n\t"
    "global_load_dword %3, %17, off offset:2048 sc0 sc1\n\t"
    "global_load_dword %4, %18, off sc0 sc1\n\t"
    "global_load_dword %5, %18, off offset:2048 sc0 sc1\n\t"
    "global_load_dword %6, %19, off sc0 sc1\n\t"
    "global_load_dword %7, %19, off offset:2048 sc0 sc1\n\t"
    "global_load_dword %8, %20, off sc0 sc1\n\t"
    "global_load_dword %9, %20, off offset:2048 sc0 sc1\n\t"
    "global_load_dword %10, %21, off sc0 sc1\n\t"
    "global_load_dword %11, %21, off offset:2048 sc0 sc1\n\t"
    "global_load_dword %12, %22, off sc0 sc1\n\t"
    "global_load_dword %13, %22, off offset:2048 sc0 sc1\n\t"
    "global_load_dword %14, %23, off sc0 sc1\n\t"
    "global_load_dword %15, %23, off offset:2048 sc0 sc1\n\t"
    "s_waitcnt vmcnt(0)"
    : "=&v"(oa[0]), "=&v"(oa[1]), "=&v"(oa[2]), "=&v"(oa[3]),
      "=&v"(oa[4]), "=&v"(oa[5]), "=&v"(oa[6]), "=&v"(oa[7]),
      "=&v"(ob[0]), "=&v"(ob[1]), "=&v"(ob[2]), "=&v"(ob[3]),
      "=&v"(ob[4]), "=&v"(ob[5]), "=&v"(ob[6]), "=&v"(ob[7])
    : "v"(a), "v"(a + 1024), "v"(a + 2048), "v"(a + 3072),
      "v"(b), "v"(b + 1024), "v"(b + 2048), "v"(b + 3072)
    : "memory");
}
// paired (8 cp + ms) x 2 gather, ONE waitcnt
__device__ __forceinline__ void ld_cpms2(const float* c0, const float* m0,
                                         const float* c1, const float* m1,
                                         float* oa, float* ob, f32x2* msa, f32x2* msb) {
  asm volatile(
    "global_load_dword %0, %18, off sc0 sc1\n\t"
    "global_load_dword %1, %18, off offset:2048 sc0 sc1\n\t"
    "global_load_dword %2, %19, off sc0 sc1\n\t"
    "global_load_dword %3, %19, off offset:2048 sc0 sc1\n\t"
    "global_load_dword %4, %20, off sc0 sc1\n\t"
    "global_load_dword %5, %20, off offset:2048 sc0 sc1\n\t"
    "global_load_dword %6, %21, off sc0 sc1\n\t"
    "global_load_dword %7, %21, off offset:2048 sc0 sc1\n\t"
    "global_load_dword %8, %22, off sc0 sc1\n\t"
    "global_load_dword %9, %22, off offset:2048 sc0 sc1\n\t"
    "global_load_dword %10, %23, off sc0 sc1\n\t"
    "global_load_dword %11, %23, off offset:2048 sc0 sc1\n\t"
    "global_load_dword %12, %24, off sc0 sc1\n\t"
    "global_load_dword %13, %24, off offset:2048 sc0 sc1\n\t"
    "global_load_dword %14, %25, off sc0 sc1\n\t"
    "global_load_dword %15, %25, off offset:2048 sc0 sc1\n\t"
    "global_load_dwordx2 %16, %26, off sc0 sc1\n\t"
    "global_load_dwordx2 %17, %27, off sc0 sc1\n\t"
    "s_waitcnt vmcnt(0)"
    : "=&v"(oa[0]), "=&v"(oa[1]), "=&v"(oa[2]), "=&v"(oa[3]),
      "=&v"(oa[4]), "=&v"(oa[5]), "=&v"(oa[6]), "=&v"(oa[7]),
      "=&v"(ob[0]), "=&v"(ob[1]), "=&v"(ob[2]), "=&v"(ob[3]),
      "=&v"(ob[4]), "=&v"(ob[5]), "=&v"(ob[6]), "=&v"(ob[7]),
      "=&v"(*msa), "=&v"(*msb)
    : "v"(c0), "v"(c0 + 1024), "v"(c0 + 2048), "v"(c0 + 3072),
      "v"(c1), "v"(c1 + 1024), "v"(c1 + 2048), "v"(c1 + 3072),
      "v"(m0), "v"(m1)
    : "memory");
}

// poll BOTH instances' 8 tags in one lane-parallel load (lanes 0-7 / 8-15)
__device__ __forceinline__ void poll2(const int* t0, const int* t1, int target,
                                      int* dead_lds) {
  int lane = threadIdx.x & 63;
  const int* tp = (lane < 8) ? (t0 + lane) : (t1 + (lane & 7));
  int it = 0;
  for (;;) {
    int f = target;
    if (lane < 16) f = ld_tag(tp);
    if (__ballot(f >= target) == ~0ull) break;
    __builtin_amdgcn_s_sleep(1);
    if (++it > (1 << 17)) { *dead_lds = 1; break; }
  }
}

__device__ __forceinline__ float dot8(f16x8 w, const float* x) {
  return (float)w[0]*x[0] + (float)w[1]*x[1] + (float)w[2]*x[2] + (float)w[3]*x[3]
       + (float)w[4]*x[4] + (float)w[5]*x[5] + (float)w[6]*x[6] + (float)w[7]*x[7];
}

// ---- K1: tokens -> embedding -> g_e = e @ W_e^T + b0 ----
__global__ __launch_bounds__(256) void k_embed_gates(
    const int* __restrict__ dec, const float* __restrict__ emb,
    const float* __restrict__ Wih0, const float* __restrict__ b0,
    float* __restrict__ ge)
{
  __shared__ float e_lds[8][64];
  int tid = threadIdx.x;
  int tb0 = blockIdx.x * 8;
  for (int j = tid; j < 8 * 64; j += 256) {
    int q = j >> 6, d = j & 63;
    int tb = tb0 + q;
    int t = tb >> 5, b = tb & 31;
    int tok;
    if (t == 0) tok = 1;
    else { tok = dec[b * 256 + (t - 1)]; if (tok == 2) tok = 0; }
    e_lds[q][d] = emb[(size_t)tok * 64 + d];
  }
  __syncthreads();
  for (int rr = 0; rr < 4; ++rr) {
    int row = tid + rr * 256;
    float bv = b0[row];
    float acc[8];
#pragma unroll
    for (int q = 0; q < 8; ++q) acc[q] = bv;
    const float* wr = Wih0 + (size_t)row * 576;
#pragma unroll 4
    for (int d4 = 0; d4 < 16; ++d4) {
      float4 w = *(const float4*)&wr[d4 * 4];
#pragma unroll
      for (int q = 0; q < 8; ++q) {
        acc[q] += w.x * e_lds[q][d4 * 4 + 0];
        acc[q] += w.y * e_lds[q][d4 * 4 + 1];
        acc[q] += w.z * e_lds[q][d4 * 4 + 2];
        acc[q] += w.w * e_lds[q][d4 * 4 + 3];
      }
    }
#pragma unroll
    for (int q = 0; q < 8; ++q) ge[(size_t)(tb0 + q) * 1024 + row] = acc[q];
  }
}

// ---- K1b: W_out fp32 -> fp16, padded ----
__global__ __launch_bounds__(256) void k_wout_f16(const float* __restrict__ W, f16* __restrict__ wo)
{
  size_t base = (size_t)blockIdx.x * 4096 + (size_t)threadIdx.x * 16;
  for (int i = 0; i < 16; ++i) {
    size_t idx = base + i;
    size_t n = idx >> 10;
    float v = (n < 10000) ? W[idx] : 0.f;
    wo[idx] = (f16)v;
  }
}

// ---- K2: 8 slices x 512 threads; TWO batch elements per block (b, b+16). ----
// Weight registers shared across the pair; exchange latency shared per phase.
__global__ __launch_bounds__(512, 2) void k_seq(
    const float* __restrict__ enc, const float* __restrict__ Wih0,
    const float* __restrict__ Wih1, const float* __restrict__ b1,
    const float* __restrict__ Wproj, const float* __restrict__ bproj,
    const float* __restrict__ ge, float* __restrict__ xc,
    f16* __restrict__ pc)
{
  __shared__ f16 ench[2][KR * 512];      // 128KB
  __shared__ float ctx_lds[2][512];
  __shared__ float hbuf[2][256];
  __shared__ float projf[2][512];
  __shared__ float gred[2][96];
  __shared__ float h1buf[2][32];
  __shared__ float sc_lds[2][64];
  __shared__ float el[2][64];
  __shared__ int dead;

  int tid = threadIdx.x;
  int j = blockIdx.x;          // 0..127
  int s = j >> 4;              // slice 0..7
  int pr = j & 15;             // pair id; slices of a pair share j%8 residue
  int b0i = pr, b1i = pr + 16;
  float* xcb0 = xc + (size_t)b0i * XC_STRIDE;
  float* xcb1 = xc + (size_t)b1i * XC_STRIDE;

  int rr = tid >> 2, c4 = tid & 3;
  int rp = tid >> 3, c8 = tid & 7;

  // ---- fp16 register-stationary weights (shared by both instances) ----
  f16x8 wA[16];   // Wih0 ctx part: own gate row, 128 cols
  f16x8 wB[8];    // Wih1: own gate row, 64 cols
  f16x8 wp[4];    // Wproj: own row, 32 cols
  int rowA = 0; float b1v = 0.f;
  if (rr < 96) {
    int g = rr >> 5, d = rr & 31;
    rowA = (g == 0 ? 0 : g == 1 ? 512 : 768) + s * 32 + d;
    const float* wra = Wih0 + (size_t)rowA * 576 + 64 + c4 * 128;
#pragma unroll
    for (int i = 0; i < 16; ++i) {
      float4 x0 = ((const float4*)wra)[2 * i];
      float4 x1 = ((const float4*)wra)[2 * i + 1];
      f16x8 w;
      w[0]=(f16)x0.x; w[1]=(f16)x0.y; w[2]=(f16)x0.z; w[3]=(f16)x0.w;
      w[4]=(f16)x1.x; w[5]=(f16)x1.y; w[6]=(f16)x1.z; w[7]=(f16)x1.w;
      wA[i] = w;
    }
    const float* wrb = Wih1 + (size_t)rowA * 256 + c4 * 64;
#pragma unroll
    for (int i = 0; i < 8; ++i) {
      float4 x0 = ((const float4*)wrb)[2 * i];
      float4 x1 = ((const float4*)wrb)[2 * i + 1];
      f16x8 w;
      w[0]=(f16)x0.x; w[1]=(f16)x0.y; w[2]=(f16)x0.z; w[3]=(f16)x0.w;
      w[4]=(f16)x1.x; w[5]=(f16)x1.y; w[6]=(f16)x1.z; w[7]=(f16)x1.w;
      wB[i] = w;
    }
    b1v = b1[rowA];
  }
  {
    const float* wpr = Wproj + (size_t)tid * 256 + s * 32;
#pragma unroll
    for (int i = 0; i < 4; ++i) {
      float4 x0 = ((const float4*)wpr)[2 * i];
      float4 x1 = ((const float4*)wpr)[2 * i + 1];
      f16x8 w;
      w[0]=(f16)x0.x; w[1]=(f16)x0.y; w[2]=(f16)x0.z; w[3]=(f16)x0.w;
      w[4]=(f16)x1.x; w[5]=(f16)x1.y; w[6]=(f16)x1.z; w[7]=(f16)x1.w;
      wp[i] = w;
    }
  }
  float bpv = bproj[tid];

  // stationary enc slices (both instances) -> LDS fp16, xor swizzle
#pragma unroll
  for (int ii = 0; ii < 2; ++ii) {
    int bb = pr + ii * 16;
    for (int i = tid; i < KR * 512; i += 512) {
      int kk = i >> 9, d = i & 511;
      float v = enc[((size_t)bb * 512 + s * KR + kk) * 512 + d];
      ench[ii][kk * 512 + (d ^ ((kk & 7) << 3))] = (f16)v;
    }
  }
  ctx_lds[0][tid] = 0.f;
  ctx_lds[1][tid] = 0.f;
  if (tid == 0) dead = 0;
  __syncthreads();

  float gev0 = 0.f, gev1 = 0.f;
  if (rr < 96 && c4 == 0) {
    gev0 = ge[(size_t)b0i * 1024 + rowA];
    gev1 = ge[(size_t)b1i * 1024 + rowA];
  }

  for (int t = 0; t < TT; ++t) {
    float* P0 = xcb0 + (t & 1) * PAR_STRIDE;
    float* P1 = xcb1 + (t & 1) * PAR_STRIDE;
    int tag = t + 1;

    // ---- stage A: gates0 both; post h0 (wave0 -> inst0, wave7 -> inst1) ----
    if (rr < 96) {
      float a0 = 0.f, a1 = 0.f;
#pragma unroll
      for (int i = 0; i < 16; ++i) {
        a0 += dot8(wA[i], &ctx_lds[0][c4 * 128 + i * 8]);
        a1 += dot8(wA[i], &ctx_lds[1][c4 * 128 + i * 8]);
      }
      a0 += __shfl_xor(a0, 1, 64); a0 += __shfl_xor(a0, 2, 64);
      a1 += __shfl_xor(a1, 1, 64); a1 += __shfl_xor(a1, 2, 64);
      if (c4 == 0) { gred[0][rr] = a0 + gev0; gred[1][rr] = a1 + gev1; }
    }
    __syncthreads();
    if (tid < 32) {
      float cc = sigm(gred[0][tid]) * tanhf(gred[0][32 + tid]);
      float h = sigm(gred[0][64 + tid]) * tanhf(cc);
      st1w(P0 + H0_OFF + s * 32 + tid, h);
      if (tid == 0) st_tag((int*)(P0 + T1_OFF) + s, tag);
    } else if (tid >= 480) {
      int u = tid - 480;
      float cc = sigm(gred[1][u]) * tanhf(gred[1][32 + u]);
      float h = sigm(gred[1][64 + u]) * tanhf(cc);
      st1w(P1 + H0_OFF + s * 32 + u, h);
      if (u == 0) st_tag((int*)(P1 + T1_OFF) + s, tag);
    }
    poll2((const int*)(P0 + T1_OFF), (const int*)(P1 + T1_OFF), tag, &dead);

    // prefetch next ge (plain cached loads; fold into next gather's waitcnt)
    if (t + 1 < TT && rr < 96 && c4 == 0) {
      gev0 = ge[(size_t)((t + 1) * 32 + b0i) * 1024 + rowA];
      gev1 = ge[(size_t)((t + 1) * 32 + b1i) * 1024 + rowA];
    }

    // ---- stage B: gather h0 both (thread-split), h1 both, proj-part post ----
    {
      const float* src = (tid < 256) ? (P0 + H0_OFF + tid) : (P1 + H0_OFF + (tid - 256));
      float hv = ld1(src);
      if (tid < 256) hbuf[0][tid] = hv; else hbuf[1][tid - 256] = hv;
    }
    __syncthreads();
    if (dead) break;
    if (rr < 96) {
      float a0 = 0.f, a1 = 0.f;
#pragma unroll
      for (int i = 0; i < 8; ++i) {
        a0 += dot8(wB[i], &hbuf[0][c4 * 64 + i * 8]);
        a1 += dot8(wB[i], &hbuf[1][c4 * 64 + i * 8]);
      }
      a0 += __shfl_xor(a0, 1, 64); a0 += __shfl_xor(a0, 2, 64);
      a1 += __shfl_xor(a1, 1, 64); a1 += __shfl_xor(a1, 2, 64);
      if (c4 == 0) { gred[0][rr] = a0 + b1v; gred[1][rr] = a1 + b1v; }
    }
    __syncthreads();
    if (tid < 32) {
      float cc = sigm(gred[0][tid]) * tanhf(gred[0][32 + tid]);
      h1buf[0][tid] = sigm(gred[0][64 + tid]) * tanhf(cc);
    } else if (tid < 64) {
      int u = tid - 32;
      float cc = sigm(gred[1][u]) * tanhf(gred[1][32 + u]);
      h1buf[1][u] = sigm(gred[1][64 + u]) * tanhf(cc);
    }
    __syncthreads();
    {
      float a0 = 0.f, a1 = 0.f;
#pragma unroll
      for (int i = 0; i < 4; ++i) {
        a0 += dot8(wp[i], &h1buf[0][i * 8]);
        a1 += dot8(wp[i], &h1buf[1][i * 8]);
      }
      st1w2(P0 + PP_OFF + s * 512 + tid, a0, P1 + PP_OFF + s * 512 + tid, a1);
    }
    __syncthreads();
    if (tid == 0) st_tag((int*)(P0 + T2_OFF) + s, tag);
    if (tid == 1) st_tag((int*)(P1 + T2_OFF) + s, tag);
    poll2((const int*)(P0 + T2_OFF), (const int*)(P1 + T2_OFF), tag, &dead);

    // ---- stage C: gather proj partials both (one batch) -> relu -> LDS ----
    {
      float o0[8], o1[8];
      ld8x2w(P0 + PP_OFF + tid, P1 + PP_OFF + tid, o0, o1);
      float v0 = bpv + o0[0] + o0[1] + o0[2] + o0[3] + o0[4] + o0[5] + o0[6] + o0[7];
      float v1 = bpv + o1[0] + o1[1] + o1[2] + o1[3] + o1[4] + o1[5] + o1[6] + o1[7];
      v0 = fmaxf(v0, 0.f); v1 = fmaxf(v1, 0.f);
      projf[0][tid] = v0; projf[1][tid] = v1;
      if (s == 0) {
        pc[(size_t)(b0i * 256 + t) * 1024 + tid] = (f16)v0;
        pc[(size_t)(b1i * 256 + t) * 1024 + tid] = (f16)v1;
      }
    }
    __syncthreads();

    // ---- stage D: scores both, softmax (waves 0/1), ctx partials both ----
    {
      int kk = rp;
      int swz = (kk & 7) << 3;
      float a0 = 0.f, a1 = 0.f;
#pragma unroll
      for (int j0 = 0; j0 < 8; ++j0) {
        int d = j0 * 64 + c8 * 8;
        f16x8 v0 = *(const f16x8*)&ench[0][kk * 512 + (d ^ swz)];
        f16x8 v1 = *(const f16x8*)&ench[1][kk * 512 + (d ^ swz)];
        float4 p00 = *(const float4*)&projf[0][d];
        float4 p01 = *(const float4*)&projf[0][d + 4];
        float4 p10 = *(const float4*)&projf[1][d];
        float4 p11 = *(const float4*)&projf[1][d + 4];
        a0 += (float)v0[0]*p00.x + (float)v0[1]*p00.y + (float)v0[2]*p00.z + (float)v0[3]*p00.w;
        a0 += (float)v0[4]*p01.x + (float)v0[5]*p01.y + (float)v0[6]*p01.z + (float)v0[7]*p01.w;
        a1 += (float)v1[0]*p10.x + (float)v1[1]*p10.y + (float)v1[2]*p10.z + (float)v1[3]*p10.w;
        a1 += (float)v1[4]*p11.x + (float)v1[5]*p11.y + (float)v1[6]*p11.z + (float)v1[7]*p11.w;
      }
      a0 += __shfl_xor(a0, 1, 64); a0 += __shfl_xor(a0, 2, 64); a0 += __shfl_xor(a0, 4, 64);
      a1 += __shfl_xor(a1, 1, 64); a1 += __shfl_xor(a1, 2, 64); a1 += __shfl_xor(a1, 4, 64);
      if (c8 == 0) { sc_lds[0][kk] = a0; sc_lds[1][kk] = a1; }
    }
    __syncthreads();
    if (tid < 128) {
      int ii = tid >> 6, l = tid & 63;
      float* Pm = ii ? P1 : P0;
      float v = sc_lds[ii][l];
      float m = v;
      m = fmaxf(m, __shfl_xor(m, 32, 64));
      m = fmaxf(m, __shfl_xor(m, 16, 64));
      m = fmaxf(m, __shfl_xor(m, 8, 64));
      m = fmaxf(m, __shfl_xor(m, 4, 64));
      m = fmaxf(m, __shfl_xor(m, 2, 64));
      m = fmaxf(m, __shfl_xor(m, 1, 64));
      float e = __expf(v - m);
      el[ii][l] = e;
      float S = e;
      S += __shfl_xor(S, 32, 64);
      S += __shfl_xor(S, 16, 64);
      S += __shfl_xor(S, 8, 64);
      S += __shfl_xor(S, 4, 64);
      S += __shfl_xor(S, 2, 64);
      S += __shfl_xor(S, 1, 64);
      if (l == 0) st2w(Pm + MS_OFF + 2 * s, (f32x2){m, S});
    }
    __syncthreads();
    {
      float c0 = 0.f, c1 = 0.f;
#pragma unroll 8
      for (int kk = 0; kk < 64; ++kk) {
        int off = kk * 512 + (tid ^ ((kk & 7) << 3));
        c0 += el[0][kk] * (float)ench[0][off];
        c1 += el[1][kk] * (float)ench[1][off];
      }
      st1w2(P0 + CP_OFF + s * 512 + tid, c0, P1 + CP_OFF + s * 512 + tid, c1);
    }
    __syncthreads();
    if (tid == 0) st_tag((int*)(P0 + T3_OFF) + s, tag);
    if (tid == 1) st_tag((int*)(P1 + T3_OFF) + s, tag);
    poll2((const int*)(P0 + T3_OFF), (const int*)(P1 + T3_OFF), tag, &dead);

    // ---- stage E: combine both (one 18-load batch) ----
    {
      float o0[8], o1[8]; f32x2 ms0, ms1;
      ld_cpms2(P0 + CP_OFF + tid, P0 + MS_OFF + 2 * (tid & 7),
               P1 + CP_OFF + tid, P1 + MS_OFF + 2 * (tid & 7),
               o0, o1, &ms0, &ms1);
      {
        float m = ms0[0], S = ms0[1];
        float mg = m;
        mg = fmaxf(mg, __shfl_xor(mg, 1, 8));
        mg = fmaxf(mg, __shfl_xor(mg, 2, 8));
        mg = fmaxf(mg, __shfl_xor(mg, 4, 8));
        float w = __expf(m - mg);
        float Sg = w * S;
        Sg += __shfl_xor(Sg, 1, 8);
        Sg += __shfl_xor(Sg, 2, 8);
        Sg += __shfl_xor(Sg, 4, 8);
        float inv = 1.f / Sg;
        float v = 0.f;
#pragma unroll
        for (int q = 0; q < 8; ++q) v += __shfl(w, q, 8) * o0[q];
        v *= inv;
        ctx_lds[0][tid] = v;
        if (s == 0) pc[(size_t)(b0i * 256 + t) * 1024 + 512 + tid] = (f16)v;
      }
      {
        float m = ms1[0], S = ms1[1];
        float mg = m;
        mg = fmaxf(mg, __shfl_xor(mg, 1, 8));
        mg = fmaxf(mg, __shfl_xor(mg, 2, 8));
        mg = fmaxf(mg, __shfl_xor(mg, 4, 8));
        float w = __expf(m - mg);
        float Sg = w * S;
        Sg += __shfl_xor(Sg, 1, 8);
        Sg += __shfl_xor(Sg, 2, 8);
        Sg += __shfl_xor(Sg, 4, 8);
        float inv = 1.f / Sg;
        float v = 0.f;
#pragma unroll
        for (int q = 0; q < 8; ++q) v += __shfl(w, q, 8) * o1[q];
        v *= inv;
        ctx_lds[1][tid] = v;
        if (s == 0) pc[(size_t)(b1i * 256 + t) * 1024 + 512 + tid] = (f16)v;
      }
    }
    __syncthreads();
    if (dead) break;
  }
}

// ---- K3: OUT[8192,10000] = PC[8192,1024] @ Wout16^T, fp16 MFMA ----
__global__ __launch_bounds__(256) void k_gemm(
    const f16* __restrict__ A, const f16* __restrict__ Bm, float* __restrict__ C)
{
  __shared__ f16 Ah[128 * 40];
  __shared__ f16 Bh[128 * 40];
  int tid = threadIdx.x;
  int tn = blockIdx.x;
  int tm = blockIdx.y;
  int lane = tid & 63, wave = tid >> 6;
  int wm = wave >> 1, wn = wave & 1;
  f32x4 acc[4][4];
#pragma unroll
  for (int i = 0; i < 4; ++i)
#pragma unroll
    for (int q = 0; q < 4; ++q) acc[i][q] = (f32x4){0.f, 0.f, 0.f, 0.f};

  for (int k0 = 0; k0 < 1024; k0 += 32) {
#pragma unroll
    for (int rd = 0; rd < 2; ++rd) {
      int chunk = tid + rd * 256;
      int row = chunk >> 2, cc = (chunk & 3) * 8;
      *(f16x8*)&Ah[row * 40 + cc] = *(const f16x8*)&A[((size_t)(tm * 128 + row)) * 1024 + k0 + cc];
      *(f16x8*)&Bh[row * 40 + cc] = *(const f16x8*)&Bm[((size_t)(tn * 128 + row)) * 1024 + k0 + cc];
    }
    __syncthreads();
    f16x8 af[4], bf[4];
#pragma unroll
    for (int q = 0; q < 4; ++q) {
      af[q] = *(const f16x8*)&Ah[(wm * 64 + q * 16 + (lane & 15)) * 40 + (lane >> 4) * 8];
      bf[q] = *(const f16x8*)&Bh[(wn * 64 + q * 16 + (lane & 15)) * 40 + (lane >> 4) * 8];
    }
#pragma unroll
    for (int i = 0; i < 4; ++i)
#pragma unroll
      for (int q = 0; q < 4; ++q)
        acc[i][q] = __builtin_amdgcn_mfma_f32_16x16x32_f16(af[i], bf[q], acc[i][q], 0, 0, 0);
    __syncthreads();
  }

  int rbase = (lane >> 4) * 4;
  int nloc = lane & 15;
#pragma unroll
  for (int i = 0; i < 4; ++i)
#pragma unroll
    for (int q = 0; q < 4; ++q)
#pragma unroll
      for (int rr = 0; rr < 4; ++rr) {
        int m = tm * 128 + wm * 64 + i * 16 + rbase + rr;
        int n = tn * 128 + wn * 64 + q * 16 + nloc;
        if (n < 10000) C[(size_t)m * 10000 + n] = acc[i][q][rr];
      }
}

extern "C" void kernel_launch(void* const* d_in, const int* in_sizes, int n_in,
                              void* d_out, int out_size, void* d_ws, size_t ws_size,
                              hipStream_t stream)
{
  const float* enc   = (const float*)d_in[0];
  const int*   dec   = (const int*)d_in[1];
  const float* emb   = (const float*)d_in[2];
  const float* Wih0  = (const float*)d_in[3];
  const float* b0    = (const float*)d_in[4];
  const float* Wih1  = (const float*)d_in[5];
  const float* b1    = (const float*)d_in[6];
  const float* Wproj = (const float*)d_in[7];
  const float* bproj = (const float*)d_in[8];
  const float* Wout  = (const float*)d_in[9];
  float* out = (float*)d_out;
  char* ws = (char*)d_ws;

  // zero the exchange region (tags must start at 0)
  hipMemsetAsync(ws + XC_OFF, 0, XC_BYTES, stream);
  k_embed_gates<<<1024, 256, 0, stream>>>(dec, emb, Wih0, b0, (float*)(ws + GE_OFF));
  k_wout_f16<<<(NPAD * 1024) / 4096, 256, 0, stream>>>(Wout, (f16*)(ws + WO_OFF));
  k_seq<<<128, 512, 0, stream>>>(enc, Wih0, Wih1, b1, Wproj, bproj,
                                 (float*)(ws + GE_OFF), (float*)(ws + XC_OFF),
                                 (f16*)(ws + PC_OFF));
  dim3 g3(79, 64);
  k_gemm<<<g3, 256, 0, stream>>>((const f16*)(ws + PC_OFF), (const f16*)(ws + WO_OFF), out);
}